// Round 1
// baseline (1149.927 us; speedup 1.0000x reference)
//
#include <hip/hip_runtime.h>

#define LN_EPS 1e-5f

typedef unsigned short u16;
typedef u16 u16x8 __attribute__((ext_vector_type(8)));
typedef __bf16 bf16x8 __attribute__((ext_vector_type(8)));
typedef float f32x4 __attribute__((ext_vector_type(4)));

__device__ __forceinline__ u16 f2bf(float f){
  unsigned u = __builtin_bit_cast(unsigned, f);
  unsigned r = (u + 0x7FFFu + ((u >> 16) & 1u)) >> 16;
  return (u16)r;
}
__device__ __forceinline__ float bf2f(u16 b){
  unsigned u = ((unsigned)b) << 16;
  return __builtin_bit_cast(float, u);
}
__device__ __forceinline__ f32x4 mfma16(u16x8 a, u16x8 b, f32x4 c){
  return __builtin_amdgcn_mfma_f32_16x16x32_bf16(
      __builtin_bit_cast(bf16x8, a), __builtin_bit_cast(bf16x8, b), c, 0, 0, 0);
}
// LDS h-tile: [64 rows][512 k] bf16, XOR swizzle on k (8-elem granules) to avoid
// 16-way bank conflicts on stride-1024B ds_read_b128.
__device__ __forceinline__ int uidx(int row, int k){
  return row * 512 + (k ^ ((row & 7) << 3));
}

__device__ __forceinline__ void zero_acc(f32x4 (&acc)[4][8]){
  #pragma unroll
  for (int mt = 0; mt < 4; ++mt)
    #pragma unroll
    for (int ct = 0; ct < 8; ++ct){
      f32x4 z = {0.f, 0.f, 0.f, 0.f};
      acc[mt][ct] = z;
    }
}

// GEMM: [64 rows in LDS hA] x [512x512 packed weights] -> acc (wave covers 128 cols)
__device__ __forceinline__ void gemm_lds(const u16* hA, const u16* __restrict__ Bp,
                                         f32x4 (&acc)[4][8], int wave, int lane){
  int lrow = lane & 15, lhi = lane >> 4;
  for (int kt = 0; kt < 16; ++kt){
    u16x8 af[4];
    #pragma unroll
    for (int mt = 0; mt < 4; ++mt)
      af[mt] = *(const u16x8*)&hA[uidx(mt * 16 + lrow, kt * 32 + lhi * 8)];
    #pragma unroll
    for (int ct = 0; ct < 8; ++ct){
      int ctg = wave * 8 + ct;
      u16x8 bv = *(const u16x8*)&Bp[(((size_t)kt * 32 + ctg) * 64 + lane) * 8];
      #pragma unroll
      for (int mt = 0; mt < 4; ++mt)
        acc[mt][ct] = mfma16(af[mt], bv, acc[mt][ct]);
    }
  }
}

__device__ __forceinline__ void add_bias(f32x4 (&acc)[4][8], const float* __restrict__ b,
                                         int wave, int lane){
  int lrow = lane & 15;
  #pragma unroll
  for (int ct = 0; ct < 8; ++ct){
    float bb = b[wave * 128 + ct * 16 + lrow];
    #pragma unroll
    for (int mt = 0; mt < 4; ++mt)
      #pragma unroll
      for (int r = 0; r < 4; ++r) acc[mt][ct][r] += bb;
  }
}

// acc += b2; LayerNorm over 512 cols per row; relu; write bf16 h3 into hA (swizzled).
__device__ __forceinline__ void ln_relu_to_lds(f32x4 (&acc)[4][8], u16* hA,
    float (*stats)[8], float (*mufb)[2],
    const float* __restrict__ b2, const float* __restrict__ g, const float* __restrict__ bt,
    int wave, int lane, int tid)
{
  int lrow = lane & 15, lhi = lane >> 4;
  float s1[4][4], s2[4][4];
  #pragma unroll
  for (int mt = 0; mt < 4; ++mt)
    #pragma unroll
    for (int r = 0; r < 4; ++r){ s1[mt][r] = 0.f; s2[mt][r] = 0.f; }
  #pragma unroll
  for (int ct = 0; ct < 8; ++ct){
    int c = wave * 128 + ct * 16 + lrow;
    float bb = b2[c];
    #pragma unroll
    for (int mt = 0; mt < 4; ++mt)
      #pragma unroll
      for (int r = 0; r < 4; ++r){
        float x = acc[mt][ct][r] + bb;
        acc[mt][ct][r] = x;
        s1[mt][r] += x; s2[mt][r] += x * x;
      }
  }
  #pragma unroll
  for (int off = 1; off < 16; off <<= 1){
    #pragma unroll
    for (int mt = 0; mt < 4; ++mt)
      #pragma unroll
      for (int r = 0; r < 4; ++r){
        s1[mt][r] += __shfl_xor(s1[mt][r], off);
        s2[mt][r] += __shfl_xor(s2[mt][r], off);
      }
  }
  // static-index selection (avoid runtime-indexed register arrays -> scratch)
  float sel1 = 0.f, sel2 = 0.f;
  #pragma unroll
  for (int mt = 0; mt < 4; ++mt)
    #pragma unroll
    for (int r = 0; r < 4; ++r)
      if (lrow == mt * 4 + r){ sel1 = s1[mt][r]; sel2 = s2[mt][r]; }
  int srow = (lrow >> 2) * 16 + lhi * 4 + (lrow & 3);
  stats[srow][wave * 2]     = sel1;
  stats[srow][wave * 2 + 1] = sel2;
  __syncthreads();              // also guarantees all waves finished reading hA (GEMM1)
  if (tid < 64){
    float a = 0.f, b = 0.f;
    #pragma unroll
    for (int w = 0; w < 4; ++w){ a += stats[tid][2 * w]; b += stats[tid][2 * w + 1]; }
    float mu  = a * (1.f / 512.f);
    float var = b * (1.f / 512.f) - mu * mu;
    mufb[tid][0] = mu;
    mufb[tid][1] = rsqrtf(fmaxf(var, 0.f) + LN_EPS);
  }
  __syncthreads();
  float gv[8], btv[8];
  #pragma unroll
  for (int ct = 0; ct < 8; ++ct){
    int c = wave * 128 + ct * 16 + lrow;
    gv[ct] = g[c]; btv[ct] = bt[c];
  }
  #pragma unroll
  for (int mt = 0; mt < 4; ++mt)
    #pragma unroll
    for (int r = 0; r < 4; ++r){
      int row = mt * 16 + lhi * 4 + r;
      float mu = mufb[row][0], rs = mufb[row][1];
      #pragma unroll
      for (int ct = 0; ct < 8; ++ct){
        int c = wave * 128 + ct * 16 + lrow;
        float x = (acc[mt][ct][r] - mu) * rs * gv[ct] + btv[ct];
        hA[uidx(row, c)] = f2bf(fmaxf(x, 0.f));
      }
    }
  __syncthreads();
}

// dot each row with head weight w; leaves per-wave partial in stats[row][wave]
__device__ __forceinline__ void head_partial(f32x4 (&acc)[4][8], const float* __restrict__ w,
                                             float (*stats)[8], int wave, int lane)
{
  int lrow = lane & 15, lhi = lane >> 4;
  float hs[4][4];
  #pragma unroll
  for (int mt = 0; mt < 4; ++mt)
    #pragma unroll
    for (int r = 0; r < 4; ++r) hs[mt][r] = 0.f;
  #pragma unroll
  for (int ct = 0; ct < 8; ++ct){
    int c = wave * 128 + ct * 16 + lrow;
    float f = w[c];
    #pragma unroll
    for (int mt = 0; mt < 4; ++mt)
      #pragma unroll
      for (int r = 0; r < 4; ++r) hs[mt][r] += acc[mt][ct][r] * f;
  }
  #pragma unroll
  for (int off = 1; off < 16; off <<= 1)
    #pragma unroll
    for (int mt = 0; mt < 4; ++mt)
      #pragma unroll
      for (int r = 0; r < 4; ++r) hs[mt][r] += __shfl_xor(hs[mt][r], off);
  float sel = 0.f;
  #pragma unroll
  for (int mt = 0; mt < 4; ++mt)
    #pragma unroll
    for (int r = 0; r < 4; ++r)
      if (lrow == mt * 4 + r) sel = hs[mt][r];
  int srow = (lrow >> 2) * 16 + lhi * 4 + (lrow & 3);
  stats[srow][wave] = sel;
}

// One block per graph: 49 edges (padded to 64 rows).
// h1 = relu(P[i]+Q[j]+b1) -> GEMM w2 -> +b2 -> LN -> relu -> GEMM w3 -> +b3
// PASS 0: agg[v] = sum_j edge_attr (bf16 out).  PASS 1: edge head -> out[g][7+e].
template<int PASS>
__global__ __launch_bounds__(256, 2) void edge_kernel(
    const u16* __restrict__ PQ, const u16* __restrict__ w2p, const u16* __restrict__ w3p,
    const float* __restrict__ b1, const float* __restrict__ b2,
    const float* __restrict__ g, const float* __restrict__ bt, const float* __restrict__ b3,
    u16* __restrict__ agg, const float* __restrict__ hw, const float* __restrict__ hb,
    float* __restrict__ out)
{
  __shared__ alignas(16) u16 hA[64 * 512];
  __shared__ float stats[64][8];
  __shared__ float mufb[64][2];
  int gidx = blockIdx.x;
  int tid = threadIdx.x;
  int wave = tid >> 6, lane = tid & 63;

  // stage h1 = relu(P[i] + Q[j] + b1) as bf16 into hA
  for (int it = 0; it < 16; ++it){
    int idx = it * 256 + tid;         // 0..4095 (groups of 8 elems)
    int e  = idx >> 6;                // 0..63
    int c0 = (idx & 63) * 8;
    float v[8];
    if (e < 49){
      int i = e / 7, j = e % 7;
      const u16* Pr = PQ + ((size_t)(gidx * 7 + i)) * 1024 + c0;
      const u16* Qr = PQ + ((size_t)(gidx * 7 + j)) * 1024 + 512 + c0;
      u16x8 p8 = *(const u16x8*)Pr;
      u16x8 q8 = *(const u16x8*)Qr;
      #pragma unroll
      for (int u = 0; u < 8; ++u)
        v[u] = fmaxf(bf2f(p8[u]) + bf2f(q8[u]) + b1[c0 + u], 0.f);
    } else {
      #pragma unroll
      for (int u = 0; u < 8; ++u) v[u] = 0.f;
    }
    u16x8 o;
    #pragma unroll
    for (int u = 0; u < 8; ++u) o[u] = f2bf(v[u]);
    *(u16x8*)&hA[uidx(e, c0)] = o;
  }
  __syncthreads();

  f32x4 acc[4][8];
  zero_acc(acc);
  gemm_lds(hA, w2p, acc, wave, lane);
  ln_relu_to_lds(acc, hA, stats, mufb, b2, g, bt, wave, lane, tid);
  zero_acc(acc);
  gemm_lds(hA, w3p, acc, wave, lane);
  add_bias(acc, b3, wave, lane);

  if (PASS == 0){
    __syncthreads();  // all GEMM2 reads of hA done before overwrite
    int lrow = lane & 15, lhi = lane >> 4;
    #pragma unroll
    for (int mt = 0; mt < 4; ++mt)
      #pragma unroll
      for (int r = 0; r < 4; ++r){
        int row = mt * 16 + lhi * 4 + r;
        #pragma unroll
        for (int ct = 0; ct < 8; ++ct){
          int c = wave * 128 + ct * 16 + lrow;
          hA[uidx(row, c)] = f2bf(acc[mt][ct][r]);
        }
      }
    __syncthreads();
    for (int it = 0; it < 14; ++it){
      int idx = it * 256 + tid;      // 0..3583
      int i = idx >> 9;              // source 0..6
      int c = idx & 511;
      float s = 0.f;
      #pragma unroll
      for (int j = 0; j < 7; ++j) s += bf2f(hA[uidx(i * 7 + j, c)]);
      agg[((size_t)(gidx * 7 + i)) * 512 + c] = f2bf(s);
    }
  } else {
    head_partial(acc, hw, stats, wave, lane);
    __syncthreads();
    if (tid < 49){
      float s = hb[0];
      #pragma unroll
      for (int w = 0; w < 4; ++w) s += stats[tid][w];
      out[(size_t)gidx * 56 + 7 + tid] = s;
    }
  }
}

// Node MLP tail: 64 node rows/block; GEMM1 A direct from global r1h.
__global__ __launch_bounds__(256, 2) void node_tail(
    const u16* __restrict__ r1h, const u16* __restrict__ w2p, const u16* __restrict__ w3p,
    const float* __restrict__ b2, const float* __restrict__ g, const float* __restrict__ bt,
    const float* __restrict__ b3, const float* __restrict__ hw, const float* __restrict__ hb,
    u16* __restrict__ node2, float* __restrict__ out)
{
  __shared__ alignas(16) u16 hA[64 * 512];
  __shared__ float stats[64][8];
  __shared__ float mufb[64][2];
  int tid = threadIdx.x;
  int wave = tid >> 6, lane = tid & 63;
  int lrow = lane & 15, lhi = lane >> 4;
  size_t row0 = (size_t)blockIdx.x * 64;

  f32x4 acc[4][8];
  zero_acc(acc);
  for (int kt = 0; kt < 16; ++kt){
    u16x8 af[4];
    #pragma unroll
    for (int mt = 0; mt < 4; ++mt)
      af[mt] = *(const u16x8*)&r1h[(row0 + mt * 16 + lrow) * 512 + kt * 32 + lhi * 8];
    #pragma unroll
    for (int ct = 0; ct < 8; ++ct){
      int ctg = wave * 8 + ct;
      u16x8 bv = *(const u16x8*)&w2p[(((size_t)kt * 32 + ctg) * 64 + lane) * 8];
      #pragma unroll
      for (int mt = 0; mt < 4; ++mt) acc[mt][ct] = mfma16(af[mt], bv, acc[mt][ct]);
    }
  }
  ln_relu_to_lds(acc, hA, stats, mufb, b2, g, bt, wave, lane, tid);
  zero_acc(acc);
  gemm_lds(hA, w3p, acc, wave, lane);
  add_bias(acc, b3, wave, lane);

  #pragma unroll
  for (int mt = 0; mt < 4; ++mt)
    #pragma unroll
    for (int r = 0; r < 4; ++r){
      size_t grow = row0 + mt * 16 + lhi * 4 + r;
      #pragma unroll
      for (int ct = 0; ct < 8; ++ct){
        int c = wave * 128 + ct * 16 + lrow;
        node2[grow * 512 + c] = f2bf(acc[mt][ct][r]);
      }
    }
  head_partial(acc, hw, stats, wave, lane);
  __syncthreads();
  if (tid < 64){
    size_t v = row0 + tid;
    float s = hb[0];
    #pragma unroll
    for (int w = 0; w < 4; ++w) s += stats[tid][w];
    out[(v / 7) * 56 + (v % 7)] = s;
  }
}

// MODE 0: PQ = node @ w1p  (K=512, N=1024 via blockIdx.y slabs, out stride 1024, no bias)
// MODE 1: r1 = relu([node|agg] @ nw1p + b)  (K=1024 split, N=512, out stride 512)
template<int MODE>
__global__ __launch_bounds__(256, 2) void gemm64(
    const u16* __restrict__ A0, const u16* __restrict__ A1,
    const u16* __restrict__ Bp, const float* __restrict__ bias,
    u16* __restrict__ Cout)
{
  int tid = threadIdx.x;
  int wave = tid >> 6, lane = tid & 63;
  int lrow = lane & 15, lhi = lane >> 4;
  size_t row0 = (size_t)blockIdx.x * 64;
  int coff = blockIdx.y * 512;
  const int KT  = (MODE == 1) ? 32 : 16;
  const int N16 = (MODE == 0) ? 64 : 32;
  const int CW  = (MODE == 0) ? 1024 : 512;
  f32x4 acc[4][8];
  zero_acc(acc);
  for (int kt = 0; kt < KT; ++kt){
    const u16* As = A0; int kk = kt * 32;
    if (MODE == 1 && kt >= 16){ As = A1; kk = (kt - 16) * 32; }
    u16x8 af[4];
    #pragma unroll
    for (int mt = 0; mt < 4; ++mt)
      af[mt] = *(const u16x8*)&As[(row0 + mt * 16 + lrow) * 512 + kk + lhi * 8];
    #pragma unroll
    for (int ct = 0; ct < 8; ++ct){
      int ctg = (coff >> 4) + wave * 8 + ct;
      u16x8 bv = *(const u16x8*)&Bp[(((size_t)kt * N16 + ctg) * 64 + lane) * 8];
      #pragma unroll
      for (int mt = 0; mt < 4; ++mt) acc[mt][ct] = mfma16(af[mt], bv, acc[mt][ct]);
    }
  }
  #pragma unroll
  for (int ct = 0; ct < 8; ++ct){
    int c = coff + wave * 128 + ct * 16 + lrow;
    float bb = (MODE == 1) ? bias[c] : 0.f;
    #pragma unroll
    for (int mt = 0; mt < 4; ++mt)
      #pragma unroll
      for (int r = 0; r < 4; ++r){
        size_t grow = row0 + mt * 16 + lhi * 4 + r;
        float x = acc[mt][ct][r] + bb;
        if (MODE == 1) x = fmaxf(x, 0.f);
        Cout[grow * CW + c] = f2bf(x);
      }
  }
}

// Pack f32 weight [K][N] into MFMA B-fragment order (bf16):
// dst[((kt*(N/16)+ct)*64+lane)*8+j] = W[kt*32+(lane>>4)*8+j][ct*16+(lane&15)]
// w1mode: synthesize W'[k][c'] = c'<512 ? ew1[k][c'] : ew1[k+512][c'-512]  (P|Q weights)
__global__ void pack_w(const float* __restrict__ W, u16* __restrict__ dst,
                       int K, int N, int w1mode)
{
  int idx = blockIdx.x * 256 + threadIdx.x;
  int total = (K >> 5) * (N >> 4) * 64;
  if (idx >= total) return;
  int lane = idx & 63;
  int t = idx >> 6;
  int nt = N >> 4;
  int ct = t % nt;
  int kt = t / nt;
  int c  = ct * 16 + (lane & 15);
  int k0 = kt * 32 + (lane >> 4) * 8;
  u16x8 o;
  #pragma unroll
  for (int j = 0; j < 8; ++j){
    int k = k0 + j;
    float v;
    if (w1mode){
      v = (c < 512) ? W[(size_t)k * 512 + c] : W[(size_t)(k + 512) * 512 + (c - 512)];
    } else {
      v = W[(size_t)k * N + c];
    }
    o[j] = f2bf(v);
  }
  *(u16x8*)&dst[(size_t)idx * 8] = o;
}

__global__ void cast_node(const float* __restrict__ src, u16* __restrict__ dst, int n8){
  int idx = blockIdx.x * 256 + threadIdx.x;
  if (idx >= n8) return;
  const float4* s = (const float4*)src;
  float4 a = s[(size_t)idx * 2], b = s[(size_t)idx * 2 + 1];
  u16x8 o;
  o[0] = f2bf(a.x); o[1] = f2bf(a.y); o[2] = f2bf(a.z); o[3] = f2bf(a.w);
  o[4] = f2bf(b.x); o[5] = f2bf(b.y); o[6] = f2bf(b.z); o[7] = f2bf(b.w);
  *(u16x8*)&dst[(size_t)idx * 8] = o;
}

extern "C" void kernel_launch(void* const* d_in, const int* in_sizes, int n_in,
                              void* d_out, int out_size, void* d_ws, size_t ws_size,
                              hipStream_t stream)
{
  (void)in_sizes; (void)n_in; (void)out_size; (void)ws_size;
  const float* states = (const float*)d_in[0];
  const float* ew1 = (const float*)d_in[1];
  const float* eb1 = (const float*)d_in[2];
  const float* ew2 = (const float*)d_in[3];
  const float* eb2 = (const float*)d_in[4];
  const float* eg  = (const float*)d_in[5];
  const float* ebt = (const float*)d_in[6];
  const float* ew3 = (const float*)d_in[7];
  const float* eb3 = (const float*)d_in[8];
  const float* nw1 = (const float*)d_in[9];
  const float* nb1 = (const float*)d_in[10];
  const float* nw2 = (const float*)d_in[11];
  const float* nb2 = (const float*)d_in[12];
  const float* ng  = (const float*)d_in[13];
  const float* nbt = (const float*)d_in[14];
  const float* nw3 = (const float*)d_in[15];
  const float* nb3 = (const float*)d_in[16];
  const float* fnw = (const float*)d_in[17];
  const float* fnb = (const float*)d_in[18];
  const float* few = (const float*)d_in[19];
  const float* feb = (const float*)d_in[20];
  float* out = (float*)d_out;

  char* ws = (char*)d_ws;
  size_t off = 0;
  auto alloc = [&](size_t bytes) -> void* {
    void* p = ws + off;
    off += (bytes + 255) & ~(size_t)255;
    return p;
  };
  const size_t NV = 28672;  // B*n
  u16* PQ    = (u16*)alloc(NV * 1024 * 2);   // [NV][P(512)|Q(512)] bf16
  u16* nodeb = (u16*)alloc(NV * 512 * 2);
  u16* aggb  = (u16*)alloc(NV * 512 * 2);
  u16* r1h   = (u16*)alloc(NV * 512 * 2);
  u16* node2 = (u16*)alloc(NV * 512 * 2);
  u16* w1p   = (u16*)alloc(512 * 1024 * 2);
  u16* nw1p  = (u16*)alloc(1024 * 512 * 2);
  u16* w2p   = (u16*)alloc(512 * 512 * 2);
  u16* w3p   = (u16*)alloc(512 * 512 * 2);
  u16* nw2p  = (u16*)alloc(512 * 512 * 2);
  u16* nw3p  = (u16*)alloc(512 * 512 * 2);

  pack_w<<<256, 256, 0, stream>>>(ew1, w1p, 512, 1024, 1);
  pack_w<<<256, 256, 0, stream>>>(nw1, nw1p, 1024, 512, 0);
  pack_w<<<128, 256, 0, stream>>>(ew2, w2p, 512, 512, 0);
  pack_w<<<128, 256, 0, stream>>>(ew3, w3p, 512, 512, 0);
  pack_w<<<128, 256, 0, stream>>>(nw2, nw2p, 512, 512, 0);
  pack_w<<<128, 256, 0, stream>>>(nw3, nw3p, 512, 512, 0);
  cast_node<<<7168, 256, 0, stream>>>(states, nodeb, (int)(NV * 512 / 8));

  // Pass 1
  gemm64<0><<<dim3(448, 2), 256, 0, stream>>>(nodeb, nullptr, w1p, nullptr, PQ);
  edge_kernel<0><<<4096, 256, 0, stream>>>(PQ, w2p, w3p, eb1, eb2, eg, ebt, eb3,
                                           aggb, nullptr, nullptr, nullptr);
  // Node update
  gemm64<1><<<dim3(448, 1), 256, 0, stream>>>(nodeb, aggb, nw1p, nb1, r1h);
  node_tail<<<448, 256, 0, stream>>>(r1h, nw2p, nw3p, nb2, ng, nbt, nb3,
                                     fnw, fnb, node2, out);
  // Pass 2
  gemm64<0><<<dim3(448, 2), 256, 0, stream>>>(node2, nullptr, w1p, nullptr, PQ);
  edge_kernel<1><<<4096, 256, 0, stream>>>(PQ, w2p, w3p, eb1, eb2, eg, ebt, eb3,
                                           nullptr, few, feb, out);
}

// Round 2
// 1104.973 us; speedup vs baseline: 1.0407x; 1.0407x over previous
//
#include <hip/hip_runtime.h>

#define LN_EPS 1e-5f

typedef unsigned short u16;
typedef u16 u16x8 __attribute__((ext_vector_type(8)));
typedef u16 u16x4 __attribute__((ext_vector_type(4)));
typedef __bf16 bf16x8 __attribute__((ext_vector_type(8)));
typedef float f32x4 __attribute__((ext_vector_type(4)));

__device__ __forceinline__ u16 f2bf(float f){
  return __builtin_bit_cast(u16, (__bf16)f);   // v_cvt RTNE, compiler packs pairs
}
__device__ __forceinline__ float bf2f(u16 b){
  return (float)__builtin_bit_cast(__bf16, b);
}
__device__ __forceinline__ f32x4 mfma16(u16x8 a, u16x8 b, f32x4 c){
  return __builtin_amdgcn_mfma_f32_16x16x32_bf16(
      __builtin_bit_cast(bf16x8, a), __builtin_bit_cast(bf16x8, b), c, 0, 0, 0);
}
// LDS h-tile: [64 rows][512 k] bf16, XOR swizzle on k (8-elem granules) to avoid
// bank conflicts on stride-1024B ds_read_b128.
__device__ __forceinline__ int uidx(int row, int k){
  return row * 512 + (k ^ ((row & 7) << 3));
}

__device__ __forceinline__ void zero_acc4(f32x4 (&acc)[4][4]){
  #pragma unroll
  for (int mt = 0; mt < 4; ++mt)
    #pragma unroll
    for (int ct = 0; ct < 4; ++ct){
      f32x4 z = {0.f, 0.f, 0.f, 0.f};
      acc[mt][ct] = z;
    }
}

// 8-wave GEMM: [64 rows in LDS hA] x [512x512 packed weights]; wave owns 64 cols.
__device__ __forceinline__ void gemm_lds8(const u16* hA, const u16* __restrict__ Bp,
                                          f32x4 (&acc)[4][4], int wave, int lane){
  int lrow = lane & 15, lhi = lane >> 4;
  for (int kt = 0; kt < 16; ++kt){
    u16x8 af[4];
    #pragma unroll
    for (int mt = 0; mt < 4; ++mt)
      af[mt] = *(const u16x8*)&hA[uidx(mt * 16 + lrow, kt * 32 + lhi * 8)];
    #pragma unroll
    for (int ct = 0; ct < 4; ++ct){
      int ctg = wave * 4 + ct;
      u16x8 bv = *(const u16x8*)&Bp[(((size_t)kt * 32 + ctg) * 64 + lane) * 8];
      #pragma unroll
      for (int mt = 0; mt < 4; ++mt)
        acc[mt][ct] = mfma16(af[mt], bv, acc[mt][ct]);
    }
  }
}

__device__ __forceinline__ void add_bias8(f32x4 (&acc)[4][4], const float* __restrict__ b,
                                          int wave, int lane){
  int lrow = lane & 15;
  #pragma unroll
  for (int ct = 0; ct < 4; ++ct){
    float bb = b[wave * 64 + ct * 16 + lrow];
    #pragma unroll
    for (int mt = 0; mt < 4; ++mt)
      #pragma unroll
      for (int r = 0; r < 4; ++r) acc[mt][ct][r] += bb;
  }
}

// acc += b2; LayerNorm over 512 cols per row; relu; write bf16 into hA (swizzled).
__device__ __forceinline__ void ln_relu8(f32x4 (&acc)[4][4], u16* hA,
    float (*stats)[16], float (*mufb)[2],
    const float* __restrict__ b2, const float* __restrict__ g, const float* __restrict__ bt,
    int wave, int lane, int tid)
{
  int lrow = lane & 15, lhi = lane >> 4;
  float s1[4][4], s2[4][4];
  #pragma unroll
  for (int mt = 0; mt < 4; ++mt)
    #pragma unroll
    for (int r = 0; r < 4; ++r){ s1[mt][r] = 0.f; s2[mt][r] = 0.f; }
  #pragma unroll
  for (int ct = 0; ct < 4; ++ct){
    int c = wave * 64 + ct * 16 + lrow;
    float bb = b2[c];
    #pragma unroll
    for (int mt = 0; mt < 4; ++mt)
      #pragma unroll
      for (int r = 0; r < 4; ++r){
        float x = acc[mt][ct][r] + bb;
        acc[mt][ct][r] = x;
        s1[mt][r] += x; s2[mt][r] += x * x;
      }
  }
  #pragma unroll
  for (int off = 1; off < 16; off <<= 1){
    #pragma unroll
    for (int mt = 0; mt < 4; ++mt)
      #pragma unroll
      for (int r = 0; r < 4; ++r){
        s1[mt][r] += __shfl_xor(s1[mt][r], off);
        s2[mt][r] += __shfl_xor(s2[mt][r], off);
      }
  }
  // static-index selection (avoid runtime-indexed register arrays -> scratch)
  float sel1 = 0.f, sel2 = 0.f;
  #pragma unroll
  for (int mt = 0; mt < 4; ++mt)
    #pragma unroll
    for (int r = 0; r < 4; ++r)
      if (lrow == mt * 4 + r){ sel1 = s1[mt][r]; sel2 = s2[mt][r]; }
  int srow = (lrow >> 2) * 16 + lhi * 4 + (lrow & 3);
  stats[srow][wave * 2]     = sel1;
  stats[srow][wave * 2 + 1] = sel2;
  __syncthreads();              // also: all waves done reading hA (GEMM1)
  if (tid < 64){
    float a = 0.f, b = 0.f;
    #pragma unroll
    for (int w = 0; w < 8; ++w){ a += stats[tid][2 * w]; b += stats[tid][2 * w + 1]; }
    float mu  = a * (1.f / 512.f);
    float var = b * (1.f / 512.f) - mu * mu;
    mufb[tid][0] = mu;
    mufb[tid][1] = rsqrtf(fmaxf(var, 0.f) + LN_EPS);
  }
  __syncthreads();
  float gv[4], btv[4];
  #pragma unroll
  for (int ct = 0; ct < 4; ++ct){
    int c = wave * 64 + ct * 16 + lrow;
    gv[ct] = g[c]; btv[ct] = bt[c];
  }
  #pragma unroll
  for (int mt = 0; mt < 4; ++mt)
    #pragma unroll
    for (int r = 0; r < 4; ++r){
      int row = mt * 16 + lhi * 4 + r;
      float mu = mufb[row][0], rs = mufb[row][1];
      #pragma unroll
      for (int ct = 0; ct < 4; ++ct){
        int c = wave * 64 + ct * 16 + lrow;
        float x = (acc[mt][ct][r] - mu) * rs * gv[ct] + btv[ct];
        hA[uidx(row, c)] = f2bf(fmaxf(x, 0.f));
      }
    }
  __syncthreads();
}

// dot each row with head weight w; per-wave partial in stats[row][wave]
__device__ __forceinline__ void head_partial8(f32x4 (&acc)[4][4], const float* __restrict__ w,
                                              float (*stats)[16], int wave, int lane)
{
  int lrow = lane & 15, lhi = lane >> 4;
  float hs[4][4];
  #pragma unroll
  for (int mt = 0; mt < 4; ++mt)
    #pragma unroll
    for (int r = 0; r < 4; ++r) hs[mt][r] = 0.f;
  #pragma unroll
  for (int ct = 0; ct < 4; ++ct){
    int c = wave * 64 + ct * 16 + lrow;
    float f = w[c];
    #pragma unroll
    for (int mt = 0; mt < 4; ++mt)
      #pragma unroll
      for (int r = 0; r < 4; ++r) hs[mt][r] += acc[mt][ct][r] * f;
  }
  #pragma unroll
  for (int off = 1; off < 16; off <<= 1)
    #pragma unroll
    for (int mt = 0; mt < 4; ++mt)
      #pragma unroll
      for (int r = 0; r < 4; ++r) hs[mt][r] += __shfl_xor(hs[mt][r], off);
  float sel = 0.f;
  #pragma unroll
  for (int mt = 0; mt < 4; ++mt)
    #pragma unroll
    for (int r = 0; r < 4; ++r)
      if (lrow == mt * 4 + r) sel = hs[mt][r];
  int srow = (lrow >> 2) * 16 + lhi * 4 + (lrow & 3);
  stats[srow][wave] = sel;
}

// One block per graph, 512 threads (8 waves): 49 edges padded to 64 rows.
// h1 = relu(P[i]+Q[j]+b1) -> GEMM w2 -> +b2 -> LN -> relu -> GEMM w3 -> +b3
// PASS 0: agg[v] = sum_j edge_attr (bf16).  PASS 1: edge head -> out[g][7+e].
#define HT_STRIDE 68   // u16 stride for transposed bounce; %4==0 (b64 align), bank +2/c
template<int PASS>
__global__ __launch_bounds__(512, 4) void edge_kernel(
    const u16* __restrict__ PQ, const u16* __restrict__ w2p, const u16* __restrict__ w3p,
    const float* __restrict__ b1, const float* __restrict__ b2,
    const float* __restrict__ g, const float* __restrict__ bt, const float* __restrict__ b3,
    u16* __restrict__ agg, const float* __restrict__ hw, const float* __restrict__ hb,
    float* __restrict__ out)
{
  __shared__ alignas(16) u16 hBuf[512 * HT_STRIDE];  // hA view: 64*512; hT view: [512][68]
  __shared__ float stats[64][16];
  __shared__ float mufb[64][2];
  int gidx = blockIdx.x;
  int tid = threadIdx.x;
  int wave = tid >> 6, lane = tid & 63;
  u16* hA = hBuf;

  // stage h1 = relu(P[i] + Q[j] + b1) as bf16 into hA; e = it*8 + wave (wave-uniform)
  const float4* b1v = (const float4*)b1;
  for (int it = 0; it < 8; ++it){
    int idx = it * 512 + tid;         // 0..4095 (8-elem granules)
    int e  = idx >> 6;                // 0..63
    int c0 = (idx & 63) * 8;
    u16x8 o;
    if (e < 49){
      int i = e / 7, j = e % 7;
      u16x8 p8 = *(const u16x8*)&PQ[((size_t)(gidx * 7 + i)) * 1024 + c0];
      u16x8 q8 = *(const u16x8*)&PQ[((size_t)(gidx * 7 + j)) * 1024 + 512 + c0];
      float4 ba = b1v[c0 >> 2], bb = b1v[(c0 >> 2) + 1];
      float bias[8] = {ba.x, ba.y, ba.z, ba.w, bb.x, bb.y, bb.z, bb.w};
      #pragma unroll
      for (int u = 0; u < 8; ++u)
        o[u] = f2bf(fmaxf(bf2f(p8[u]) + bf2f(q8[u]) + bias[u], 0.f));
    } else {
      #pragma unroll
      for (int u = 0; u < 8; ++u) o[u] = 0;
    }
    *(u16x8*)&hA[uidx(e, c0)] = o;
  }
  __syncthreads();

  f32x4 acc[4][4];
  zero_acc4(acc);
  gemm_lds8(hA, w2p, acc, wave, lane);
  ln_relu8(acc, hA, stats, mufb, b2, g, bt, wave, lane, tid);
  zero_acc4(acc);
  gemm_lds8(hA, w3p, acc, wave, lane);
  add_bias8(acc, b3, wave, lane);

  if (PASS == 0){
    __syncthreads();  // all GEMM2 reads of hA done before overwrite as hT
    int lrow = lane & 15, lhi = lane >> 4;
    #pragma unroll
    for (int mt = 0; mt < 4; ++mt)
      #pragma unroll
      for (int ct = 0; ct < 4; ++ct){
        int c = wave * 64 + ct * 16 + lrow;
        u16x4 o;
        #pragma unroll
        for (int r = 0; r < 4; ++r) o[r] = f2bf(acc[mt][ct][r]);
        *(u16x4*)&hBuf[c * HT_STRIDE + mt * 16 + lhi * 4] = o;   // 8B-aligned
      }
    __syncthreads();
    // agg over j: rows 7i..7i+6 are contiguous in hT; 3 aligned b64 reads, static select
    int c = tid;  // 0..511
    #pragma unroll
    for (int i = 0; i < 7; ++i){
      int r0 = (7 * i) & ~3;
      u16x4 v0 = *(const u16x4*)&hBuf[c * HT_STRIDE + r0];
      u16x4 v1 = *(const u16x4*)&hBuf[c * HT_STRIDE + r0 + 4];
      u16x4 v2 = *(const u16x4*)&hBuf[c * HT_STRIDE + r0 + 8];
      float s = 0.f;
      #pragma unroll
      for (int j = 0; j < 7; ++j){
        int k = 7 * i + j - r0;   // 0..11, compile-time
        u16 val = (k < 4) ? v0[k] : (k < 8) ? v1[k - 4] : v2[k - 8];
        s += bf2f(val);
      }
      agg[((size_t)(gidx * 7 + i)) * 512 + c] = f2bf(s);
    }
  } else {
    head_partial8(acc, hw, stats, wave, lane);
    __syncthreads();
    if (tid < 49){
      float s = hb[0];
      #pragma unroll
      for (int w = 0; w < 8; ++w) s += stats[tid][w];
      out[(size_t)gidx * 56 + 7 + tid] = s;
    }
  }
}

// Node MLP tail: 64 node rows/block, 512 threads; GEMM1 A direct from global r1h.
__global__ __launch_bounds__(512, 4) void node_tail(
    const u16* __restrict__ r1h, const u16* __restrict__ w2p, const u16* __restrict__ w3p,
    const float* __restrict__ b2, const float* __restrict__ g, const float* __restrict__ bt,
    const float* __restrict__ b3, const float* __restrict__ hw, const float* __restrict__ hb,
    u16* __restrict__ node2, float* __restrict__ out)
{
  __shared__ alignas(16) u16 hA[64 * 512];
  __shared__ float stats[64][16];
  __shared__ float mufb[64][2];
  int tid = threadIdx.x;
  int wave = tid >> 6, lane = tid & 63;
  int lrow = lane & 15, lhi = lane >> 4;
  size_t row0 = (size_t)blockIdx.x * 64;

  f32x4 acc[4][4];
  zero_acc4(acc);
  for (int kt = 0; kt < 16; ++kt){
    u16x8 af[4];
    #pragma unroll
    for (int mt = 0; mt < 4; ++mt)
      af[mt] = *(const u16x8*)&r1h[(row0 + mt * 16 + lrow) * 512 + kt * 32 + lhi * 8];
    #pragma unroll
    for (int ct = 0; ct < 4; ++ct){
      int ctg = wave * 4 + ct;
      u16x8 bv = *(const u16x8*)&w2p[(((size_t)kt * 32 + ctg) * 64 + lane) * 8];
      #pragma unroll
      for (int mt = 0; mt < 4; ++mt) acc[mt][ct] = mfma16(af[mt], bv, acc[mt][ct]);
    }
  }
  ln_relu8(acc, hA, stats, mufb, b2, g, bt, wave, lane, tid);
  zero_acc4(acc);
  gemm_lds8(hA, w3p, acc, wave, lane);
  add_bias8(acc, b3, wave, lane);

  #pragma unroll
  for (int mt = 0; mt < 4; ++mt)
    #pragma unroll
    for (int r = 0; r < 4; ++r){
      size_t grow = row0 + mt * 16 + lhi * 4 + r;
      #pragma unroll
      for (int ct = 0; ct < 4; ++ct){
        int c = wave * 64 + ct * 16 + lrow;
        node2[grow * 512 + c] = f2bf(acc[mt][ct][r]);
      }
    }
  head_partial8(acc, hw, stats, wave, lane);
  __syncthreads();
  if (tid < 64){
    size_t v = row0 + tid;
    float s = hb[0];
    #pragma unroll
    for (int w = 0; w < 8; ++w) s += stats[tid][w];
    out[(v / 7) * 56 + (v % 7)] = s;
  }
}

// MODE 0: PQ = node @ w1p  (K=512, N=1024 via blockIdx.y slabs, out stride 1024, no bias)
// MODE 1: r1 = relu([node|agg] @ nw1p + b)  (K=1024 split, N=512, out stride 512)
template<int MODE>
__global__ __launch_bounds__(256, 2) void gemm64(
    const u16* __restrict__ A0, const u16* __restrict__ A1,
    const u16* __restrict__ Bp, const float* __restrict__ bias,
    u16* __restrict__ Cout)
{
  int tid = threadIdx.x;
  int wave = tid >> 6, lane = tid & 63;
  int lrow = lane & 15, lhi = lane >> 4;
  size_t row0 = (size_t)blockIdx.x * 64;
  int coff = blockIdx.y * 512;
  const int KT  = (MODE == 1) ? 32 : 16;
  const int N16 = (MODE == 0) ? 64 : 32;
  const int CW  = (MODE == 0) ? 1024 : 512;
  f32x4 acc[4][8];
  #pragma unroll
  for (int mt = 0; mt < 4; ++mt)
    #pragma unroll
    for (int ct = 0; ct < 8; ++ct){
      f32x4 z = {0.f, 0.f, 0.f, 0.f};
      acc[mt][ct] = z;
    }
  for (int kt = 0; kt < KT; ++kt){
    const u16* As = A0; int kk = kt * 32;
    if (MODE == 1 && kt >= 16){ As = A1; kk = (kt - 16) * 32; }
    u16x8 af[4];
    #pragma unroll
    for (int mt = 0; mt < 4; ++mt)
      af[mt] = *(const u16x8*)&As[(row0 + mt * 16 + lrow) * 512 + kk + lhi * 8];
    #pragma unroll
    for (int ct = 0; ct < 8; ++ct){
      int ctg = (coff >> 4) + wave * 8 + ct;
      u16x8 bv = *(const u16x8*)&Bp[(((size_t)kt * N16 + ctg) * 64 + lane) * 8];
      #pragma unroll
      for (int mt = 0; mt < 4; ++mt) acc[mt][ct] = mfma16(af[mt], bv, acc[mt][ct]);
    }
  }
  #pragma unroll
  for (int ct = 0; ct < 8; ++ct){
    int c = coff + wave * 128 + ct * 16 + lrow;
    float bb = (MODE == 1) ? bias[c] : 0.f;
    #pragma unroll
    for (int mt = 0; mt < 4; ++mt)
      #pragma unroll
      for (int r = 0; r < 4; ++r){
        size_t grow = row0 + mt * 16 + lhi * 4 + r;
        float x = acc[mt][ct][r] + bb;
        if (MODE == 1) x = fmaxf(x, 0.f);
        Cout[grow * CW + c] = f2bf(x);
      }
  }
}

// Pack f32 weight [K][N] into MFMA B-fragment order (bf16):
// dst[((kt*(N/16)+ct)*64+lane)*8+j] = W[kt*32+(lane>>4)*8+j][ct*16+(lane&15)]
// w1mode: W'[k][c'] = c'<512 ? ew1[k][c'] : ew1[k+512][c'-512]  (P|Q weights)
__global__ void pack_w(const float* __restrict__ W, u16* __restrict__ dst,
                       int K, int N, int w1mode)
{
  int idx = blockIdx.x * 256 + threadIdx.x;
  int total = (K >> 5) * (N >> 4) * 64;
  if (idx >= total) return;
  int lane = idx & 63;
  int t = idx >> 6;
  int nt = N >> 4;
  int ct = t % nt;
  int kt = t / nt;
  int c  = ct * 16 + (lane & 15);
  int k0 = kt * 32 + (lane >> 4) * 8;
  u16x8 o;
  #pragma unroll
  for (int j = 0; j < 8; ++j){
    int k = k0 + j;
    float v;
    if (w1mode){
      v = (c < 512) ? W[(size_t)k * 512 + c] : W[(size_t)(k + 512) * 512 + (c - 512)];
    } else {
      v = W[(size_t)k * N + c];
    }
    o[j] = f2bf(v);
  }
  *(u16x8*)&dst[(size_t)idx * 8] = o;
}

__global__ void cast_node(const float* __restrict__ src, u16* __restrict__ dst, int n8){
  int idx = blockIdx.x * 256 + threadIdx.x;
  if (idx >= n8) return;
  const float4* s = (const float4*)src;
  float4 a = s[(size_t)idx * 2], b = s[(size_t)idx * 2 + 1];
  u16x8 o;
  o[0] = f2bf(a.x); o[1] = f2bf(a.y); o[2] = f2bf(a.z); o[3] = f2bf(a.w);
  o[4] = f2bf(b.x); o[5] = f2bf(b.y); o[6] = f2bf(b.z); o[7] = f2bf(b.w);
  *(u16x8*)&dst[(size_t)idx * 8] = o;
}

extern "C" void kernel_launch(void* const* d_in, const int* in_sizes, int n_in,
                              void* d_out, int out_size, void* d_ws, size_t ws_size,
                              hipStream_t stream)
{
  (void)in_sizes; (void)n_in; (void)out_size; (void)ws_size;
  const float* states = (const float*)d_in[0];
  const float* ew1 = (const float*)d_in[1];
  const float* eb1 = (const float*)d_in[2];
  const float* ew2 = (const float*)d_in[3];
  const float* eb2 = (const float*)d_in[4];
  const float* eg  = (const float*)d_in[5];
  const float* ebt = (const float*)d_in[6];
  const float* ew3 = (const float*)d_in[7];
  const float* eb3 = (const float*)d_in[8];
  const float* nw1 = (const float*)d_in[9];
  const float* nb1 = (const float*)d_in[10];
  const float* nw2 = (const float*)d_in[11];
  const float* nb2 = (const float*)d_in[12];
  const float* ng  = (const float*)d_in[13];
  const float* nbt = (const float*)d_in[14];
  const float* nw3 = (const float*)d_in[15];
  const float* nb3 = (const float*)d_in[16];
  const float* fnw = (const float*)d_in[17];
  const float* fnb = (const float*)d_in[18];
  const float* few = (const float*)d_in[19];
  const float* feb = (const float*)d_in[20];
  float* out = (float*)d_out;

  char* ws = (char*)d_ws;
  size_t off = 0;
  auto alloc = [&](size_t bytes) -> void* {
    void* p = ws + off;
    off += (bytes + 255) & ~(size_t)255;
    return p;
  };
  const size_t NV = 28672;  // B*n
  u16* PQ    = (u16*)alloc(NV * 1024 * 2);   // [NV][P(512)|Q(512)] bf16
  u16* nodeb = (u16*)alloc(NV * 512 * 2);
  u16* aggb  = (u16*)alloc(NV * 512 * 2);
  u16* r1h   = (u16*)alloc(NV * 512 * 2);
  u16* node2 = (u16*)alloc(NV * 512 * 2);
  u16* w1p   = (u16*)alloc(512 * 1024 * 2);
  u16* nw1p  = (u16*)alloc(1024 * 512 * 2);
  u16* w2p   = (u16*)alloc(512 * 512 * 2);
  u16* w3p   = (u16*)alloc(512 * 512 * 2);
  u16* nw2p  = (u16*)alloc(512 * 512 * 2);
  u16* nw3p  = (u16*)alloc(512 * 512 * 2);

  pack_w<<<256, 256, 0, stream>>>(ew1, w1p, 512, 1024, 1);
  pack_w<<<256, 256, 0, stream>>>(nw1, nw1p, 1024, 512, 0);
  pack_w<<<128, 256, 0, stream>>>(ew2, w2p, 512, 512, 0);
  pack_w<<<128, 256, 0, stream>>>(ew3, w3p, 512, 512, 0);
  pack_w<<<128, 256, 0, stream>>>(nw2, nw2p, 512, 512, 0);
  pack_w<<<128, 256, 0, stream>>>(nw3, nw3p, 512, 512, 0);
  cast_node<<<7168, 256, 0, stream>>>(states, nodeb, (int)(NV * 512 / 8));

  // Pass 1
  gemm64<0><<<dim3(448, 2), 256, 0, stream>>>(nodeb, nullptr, w1p, nullptr, PQ);
  edge_kernel<0><<<4096, 512, 0, stream>>>(PQ, w2p, w3p, eb1, eb2, eg, ebt, eb3,
                                           aggb, nullptr, nullptr, nullptr);
  // Node update
  gemm64<1><<<dim3(448, 1), 256, 0, stream>>>(nodeb, aggb, nw1p, nb1, r1h);
  node_tail<<<448, 512, 0, stream>>>(r1h, nw2p, nw3p, nb2, ng, nbt, nb3,
                                     fnw, fnb, node2, out);
  // Pass 2
  gemm64<0><<<dim3(448, 2), 256, 0, stream>>>(node2, nullptr, w1p, nullptr, PQ);
  edge_kernel<1><<<4096, 512, 0, stream>>>(PQ, w2p, w3p, eb1, eb2, eg, ebt, eb3,
                                           nullptr, few, feb, out);
}

// Round 3
// 1104.133 us; speedup vs baseline: 1.0415x; 1.0008x over previous
//
#include <hip/hip_runtime.h>

#define LN_EPS 1e-5f

typedef unsigned short u16;
typedef u16 u16x8 __attribute__((ext_vector_type(8)));
typedef u16 u16x4 __attribute__((ext_vector_type(4)));
typedef __bf16 bf16x8 __attribute__((ext_vector_type(8)));
typedef float f32x4 __attribute__((ext_vector_type(4)));
typedef float f32x2 __attribute__((ext_vector_type(2)));

__device__ __forceinline__ u16 f2bf(float f){
  return __builtin_bit_cast(u16, (__bf16)f);
}
__device__ __forceinline__ float bf2f(u16 b){
  return (float)__builtin_bit_cast(__bf16, b);
}
__device__ __forceinline__ f32x4 mfma16(u16x8 a, u16x8 b, f32x4 c){
  return __builtin_amdgcn_mfma_f32_16x16x32_bf16(
      __builtin_bit_cast(bf16x8, a), __builtin_bit_cast(bf16x8, b), c, 0, 0, 0);
}
// LDS h-tile: [rows][512 k] bf16, XOR swizzle on k (8-elem granules):
// conflict-free-minimum for stride-1KB ds_read_b128 / staging writes.
__device__ __forceinline__ int uidx(int row, int k){
  return row * 512 + (k ^ ((row & 7) << 3));
}

template<int MT>
__device__ __forceinline__ void zero_accT(f32x4 (&acc)[MT][4]){
  #pragma unroll
  for (int mt = 0; mt < MT; ++mt)
    #pragma unroll
    for (int ct = 0; ct < 4; ++ct){
      f32x4 z = {0.f, 0.f, 0.f, 0.f};
      acc[mt][ct] = z;
    }
}

// 8-wave GEMM: [MT*16 rows in LDS hA] x [512x512 packed weights]; wave owns 64 cols.
// Each B-tile is read by exactly one wave -> block reads W once from L2.
template<int MT>
__device__ __forceinline__ void gemm_ldsT(const u16* hA, const u16* __restrict__ Bp,
                                          f32x4 (&acc)[MT][4], int wave, int lane){
  int lrow = lane & 15, lhi = lane >> 4;
  for (int kt = 0; kt < 16; ++kt){
    u16x8 af[MT];
    #pragma unroll
    for (int mt = 0; mt < MT; ++mt)
      af[mt] = *(const u16x8*)&hA[uidx(mt * 16 + lrow, kt * 32 + lhi * 8)];
    #pragma unroll
    for (int ct = 0; ct < 4; ++ct){
      u16x8 bv = *(const u16x8*)&Bp[(((size_t)kt * 32 + wave * 4 + ct) * 64 + lane) * 8];
      #pragma unroll
      for (int mt = 0; mt < MT; ++mt)
        acc[mt][ct] = mfma16(af[mt], bv, acc[mt][ct]);
    }
  }
}

template<int MT>
__device__ __forceinline__ void add_biasT(f32x4 (&acc)[MT][4], const float* __restrict__ b,
                                          int wave, int lane){
  int lrow = lane & 15;
  #pragma unroll
  for (int ct = 0; ct < 4; ++ct){
    float bb = b[wave * 64 + ct * 16 + lrow];
    #pragma unroll
    for (int mt = 0; mt < MT; ++mt)
      #pragma unroll
      for (int r = 0; r < 4; ++r) acc[mt][ct][r] += bb;
  }
}

// acc += b2; LayerNorm over 512 cols per row; relu; write bf16 into hA (swizzled).
template<int MT>
__device__ __forceinline__ void ln_reluT(f32x4 (&acc)[MT][4], u16* hA,
    f32x2 (*stats)[8], f32x2* mufb,
    const float* __restrict__ b2, const float* __restrict__ g, const float* __restrict__ bt,
    int wave, int lane, int tid)
{
  int lrow = lane & 15, lhi = lane >> 4;
  float s1[MT][4], s2[MT][4];
  #pragma unroll
  for (int mt = 0; mt < MT; ++mt)
    #pragma unroll
    for (int r = 0; r < 4; ++r){ s1[mt][r] = 0.f; s2[mt][r] = 0.f; }
  #pragma unroll
  for (int ct = 0; ct < 4; ++ct){
    int c = wave * 64 + ct * 16 + lrow;
    float bb = b2[c];
    #pragma unroll
    for (int mt = 0; mt < MT; ++mt)
      #pragma unroll
      for (int r = 0; r < 4; ++r){
        float x = acc[mt][ct][r] + bb;
        acc[mt][ct][r] = x;
        s1[mt][r] += x; s2[mt][r] += x * x;
      }
  }
  #pragma unroll
  for (int off = 1; off < 16; off <<= 1){
    #pragma unroll
    for (int mt = 0; mt < MT; ++mt)
      #pragma unroll
      for (int r = 0; r < 4; ++r){
        s1[mt][r] += __shfl_xor(s1[mt][r], off);
        s2[mt][r] += __shfl_xor(s2[mt][r], off);
      }
  }
  // lane lrow owns pair p=lrow (and p=lrow+16 when MT>4); static-index selection
  float sa1 = 0.f, sa2 = 0.f, sb1 = 0.f, sb2 = 0.f;
  #pragma unroll
  for (int mt = 0; mt < MT; ++mt)
    #pragma unroll
    for (int r = 0; r < 4; ++r){
      int p = mt * 4 + r;
      if (p < 16){ if (lrow == p){ sa1 = s1[mt][r]; sa2 = s2[mt][r]; } }
      else       { if (lrow == p - 16){ sb1 = s1[mt][r]; sb2 = s2[mt][r]; } }
    }
  int rowa = (lrow >> 2) * 16 + lhi * 4 + (lrow & 3);
  f32x2 pa = {sa1, sa2};
  stats[rowa][wave] = pa;
  if (MT * 4 > 16 && lrow < MT * 4 - 16){
    f32x2 pb = {sb1, sb2};
    stats[rowa + 64][wave] = pb;
  }
  __syncthreads();              // also: all waves done reading hA (GEMM1)
  if (tid < MT * 16){
    float a = 0.f, b = 0.f;
    #pragma unroll
    for (int w = 0; w < 8; ++w){ a += stats[tid][w][0]; b += stats[tid][w][1]; }
    float mu  = a * (1.f / 512.f);
    float var = b * (1.f / 512.f) - mu * mu;
    f32x2 mr = {mu, rsqrtf(fmaxf(var, 0.f) + LN_EPS)};
    mufb[tid] = mr;
  }
  __syncthreads();
  float gv[4], btv[4];
  #pragma unroll
  for (int ct = 0; ct < 4; ++ct){
    int c = wave * 64 + ct * 16 + lrow;
    gv[ct] = g[c]; btv[ct] = bt[c];
  }
  #pragma unroll
  for (int mt = 0; mt < MT; ++mt)
    #pragma unroll
    for (int r = 0; r < 4; ++r){
      int row = mt * 16 + lhi * 4 + r;
      f32x2 mr = mufb[row];
      #pragma unroll
      for (int ct = 0; ct < 4; ++ct){
        int c = wave * 64 + ct * 16 + lrow;
        float x = (acc[mt][ct][r] - mr[0]) * mr[1] * gv[ct] + btv[ct];
        hA[uidx(row, c)] = f2bf(fmaxf(x, 0.f));
      }
    }
  __syncthreads();
}

// dot each row with head weight w; per-wave partial -> stats[row][wave].x
template<int MT>
__device__ __forceinline__ void head_partialT(f32x4 (&acc)[MT][4], const float* __restrict__ w,
                                              f32x2 (*stats)[8], int wave, int lane)
{
  int lrow = lane & 15, lhi = lane >> 4;
  float hs[MT][4];
  #pragma unroll
  for (int mt = 0; mt < MT; ++mt)
    #pragma unroll
    for (int r = 0; r < 4; ++r) hs[mt][r] = 0.f;
  #pragma unroll
  for (int ct = 0; ct < 4; ++ct){
    int c = wave * 64 + ct * 16 + lrow;
    float f = w[c];
    #pragma unroll
    for (int mt = 0; mt < MT; ++mt)
      #pragma unroll
      for (int r = 0; r < 4; ++r) hs[mt][r] += acc[mt][ct][r] * f;
  }
  #pragma unroll
  for (int off = 1; off < 16; off <<= 1)
    #pragma unroll
    for (int mt = 0; mt < MT; ++mt)
      #pragma unroll
      for (int r = 0; r < 4; ++r) hs[mt][r] += __shfl_xor(hs[mt][r], off);
  float sa = 0.f, sb = 0.f;
  #pragma unroll
  for (int mt = 0; mt < MT; ++mt)
    #pragma unroll
    for (int r = 0; r < 4; ++r){
      int p = mt * 4 + r;
      if (p < 16){ if (lrow == p) sa = hs[mt][r]; }
      else       { if (lrow == p - 16) sb = hs[mt][r]; }
    }
  int rowa = (lrow >> 2) * 16 + lhi * 4 + (lrow & 3);
  f32x2 pa = {sa, 0.f};
  stats[rowa][wave] = pa;
  if (MT * 4 > 16 && lrow < MT * 4 - 16){
    f32x2 pb = {sb, 0.f};
    stats[rowa + 64][wave] = pb;
  }
}

// One block per TWO graphs, 512 threads (8 full-row waves), M=112 rows:
// rows [0..48] = graph 2b edges, [49..97] = graph 2b+1 edges, [98..111] pad.
// h1 = relu(P[i]+Q[j]+b1) -> GEMM w2 -> +b2 -> LN -> relu -> GEMM w3 -> +b3
// PASS 0: agg[v] = sum_j edge_attr (bf16).  PASS 1: edge head -> out[g][7+e].
#define MT_E 7
#define HT 116   // hT u16 stride (covers 112 rows + pad; rows base 8B-aligned)
template<int PASS>
__global__ __launch_bounds__(512, 2) void edge_kernel(
    const u16* __restrict__ PQ, const u16* __restrict__ w2p, const u16* __restrict__ w3p,
    const float* __restrict__ b1, const float* __restrict__ b2,
    const float* __restrict__ g, const float* __restrict__ bt, const float* __restrict__ b3,
    u16* __restrict__ agg, const float* __restrict__ hw, const float* __restrict__ hb,
    float* __restrict__ out)
{
  __shared__ alignas(16) u16 hBuf[512 * HT];  // hA view: 112*512; hT view: [512][HT]
  __shared__ f32x2 stats[112][8];
  __shared__ f32x2 mufb[112];
  int gidx = blockIdx.x;
  int tid = threadIdx.x;
  int wave = tid >> 6, lane = tid & 63;
  u16* hA = hBuf;

  // stage h1 = relu(P[i]+Q[j]+b1) as bf16 into hA; e = it*8 + wave (wave-uniform)
  const float4* b1v = (const float4*)b1;
  for (int it = 0; it < 14; ++it){
    int idx = it * 512 + tid;         // 0..7167 (8-elem granules)
    int e  = idx >> 6;                // 0..111
    int c0 = (idx & 63) * 8;
    int sub = (e >= 49) ? 1 : 0;
    int er = e - (sub ? 49 : 0);
    u16x8 o;
    if (er < 49){
      int i = er / 7, j = er % 7;
      int gg = gidx * 2 + sub;
      u16x8 p8 = *(const u16x8*)&PQ[((size_t)(gg * 7 + i)) * 1024 + c0];
      u16x8 q8 = *(const u16x8*)&PQ[((size_t)(gg * 7 + j)) * 1024 + 512 + c0];
      float4 ba = b1v[c0 >> 2], bb = b1v[(c0 >> 2) + 1];
      float bias[8] = {ba.x, ba.y, ba.z, ba.w, bb.x, bb.y, bb.z, bb.w};
      #pragma unroll
      for (int u = 0; u < 8; ++u)
        o[u] = f2bf(fmaxf(bf2f(p8[u]) + bf2f(q8[u]) + bias[u], 0.f));
    } else {
      #pragma unroll
      for (int u = 0; u < 8; ++u) o[u] = 0;
    }
    *(u16x8*)&hA[uidx(e, c0)] = o;
  }
  __syncthreads();

  f32x4 acc[MT_E][4];
  zero_accT<MT_E>(acc);
  gemm_ldsT<MT_E>(hA, w2p, acc, wave, lane);
  ln_reluT<MT_E>(acc, hA, stats, mufb, b2, g, bt, wave, lane, tid);
  zero_accT<MT_E>(acc);
  gemm_ldsT<MT_E>(hA, w3p, acc, wave, lane);
  add_biasT<MT_E>(acc, b3, wave, lane);

  if (PASS == 0){
    __syncthreads();  // all GEMM2 reads of hA done before overwrite as hT
    int lrow = lane & 15, lhi = lane >> 4;
    #pragma unroll
    for (int mt = 0; mt < MT_E; ++mt)
      #pragma unroll
      for (int ct = 0; ct < 4; ++ct){
        int c = wave * 64 + ct * 16 + lrow;
        u16x4 o;
        #pragma unroll
        for (int r = 0; r < 4; ++r) o[r] = f2bf(acc[mt][ct][r]);
        *(u16x4*)&hBuf[c * HT + mt * 16 + lhi * 4] = o;   // 8B-aligned
      }
    __syncthreads();
    // agg over j: rows rbase..rbase+6 contiguous in hT; 3 aligned b64 reads
    int c = tid;  // 0..511
    #pragma unroll
    for (int sub = 0; sub < 2; ++sub)
      #pragma unroll
      for (int i = 0; i < 7; ++i){
        const int rbase = sub * 49 + 7 * i;
        const int r0 = rbase & ~3;
        u16x4 v0 = *(const u16x4*)&hBuf[c * HT + r0];
        u16x4 v1 = *(const u16x4*)&hBuf[c * HT + r0 + 4];
        u16x4 v2 = *(const u16x4*)&hBuf[c * HT + r0 + 8];
        float s = 0.f;
        #pragma unroll
        for (int j = 0; j < 7; ++j){
          const int k = rbase + j - r0;   // compile-time after unroll
          u16 val = (k < 4) ? v0[k] : (k < 8) ? v1[k - 4] : v2[k - 8];
          s += bf2f(val);
        }
        agg[((size_t)((gidx * 2 + sub) * 7 + i)) * 512 + c] = f2bf(s);
      }
  } else {
    head_partialT<MT_E>(acc, hw, stats, wave, lane);
    __syncthreads();
    if (tid < 98){
      int sub = (tid >= 49) ? 1 : 0;
      int er = tid - (sub ? 49 : 0);
      float s = hb[0];
      #pragma unroll
      for (int w = 0; w < 8; ++w) s += stats[tid][w][0];
      out[(size_t)(gidx * 2 + sub) * 56 + 7 + er] = s;
    }
  }
}

// Node MLP tail: 64 node rows/block, 512 threads; GEMM1 A direct from global r1h.
__global__ __launch_bounds__(512, 4) void node_tail(
    const u16* __restrict__ r1h, const u16* __restrict__ w2p, const u16* __restrict__ w3p,
    const float* __restrict__ b2, const float* __restrict__ g, const float* __restrict__ bt,
    const float* __restrict__ b3, const float* __restrict__ hw, const float* __restrict__ hb,
    u16* __restrict__ node2, float* __restrict__ out)
{
  __shared__ alignas(16) u16 hA[64 * 512];
  __shared__ f32x2 stats[64][8];
  __shared__ f32x2 mufb[64];
  int tid = threadIdx.x;
  int wave = tid >> 6, lane = tid & 63;
  int lrow = lane & 15, lhi = lane >> 4;
  size_t row0 = (size_t)blockIdx.x * 64;

  f32x4 acc[4][4];
  zero_accT<4>(acc);
  for (int kt = 0; kt < 16; ++kt){
    u16x8 af[4];
    #pragma unroll
    for (int mt = 0; mt < 4; ++mt)
      af[mt] = *(const u16x8*)&r1h[(row0 + mt * 16 + lrow) * 512 + kt * 32 + lhi * 8];
    #pragma unroll
    for (int ct = 0; ct < 4; ++ct){
      u16x8 bv = *(const u16x8*)&w2p[(((size_t)kt * 32 + wave * 4 + ct) * 64 + lane) * 8];
      #pragma unroll
      for (int mt = 0; mt < 4; ++mt) acc[mt][ct] = mfma16(af[mt], bv, acc[mt][ct]);
    }
  }
  ln_reluT<4>(acc, hA, stats, mufb, b2, g, bt, wave, lane, tid);
  zero_accT<4>(acc);
  gemm_ldsT<4>(hA, w3p, acc, wave, lane);
  add_biasT<4>(acc, b3, wave, lane);

  #pragma unroll
  for (int mt = 0; mt < 4; ++mt)
    #pragma unroll
    for (int r = 0; r < 4; ++r){
      size_t grow = row0 + mt * 16 + lhi * 4 + r;
      #pragma unroll
      for (int ct = 0; ct < 4; ++ct){
        int c = wave * 64 + ct * 16 + lrow;
        node2[grow * 512 + c] = f2bf(acc[mt][ct][r]);
      }
    }
  head_partialT<4>(acc, hw, stats, wave, lane);
  __syncthreads();
  if (tid < 64){
    size_t v = row0 + tid;
    float s = hb[0];
    #pragma unroll
    for (int w = 0; w < 8; ++w) s += stats[tid][w][0];
    out[(v / 7) * 56 + (v % 7)] = s;
  }
}

// MODE 0: PQ = node @ w1p  (K=512, N=1024 via blockIdx.y slabs, out stride 1024, no bias)
// MODE 1: r1 = relu([node|agg] @ nw1p + b)  (K=1024 split, N=512, out stride 512)
template<int MODE>
__global__ __launch_bounds__(256, 2) void gemm64(
    const u16* __restrict__ A0, const u16* __restrict__ A1,
    const u16* __restrict__ Bp, const float* __restrict__ bias,
    u16* __restrict__ Cout)
{
  int tid = threadIdx.x;
  int wave = tid >> 6, lane = tid & 63;
  int lrow = lane & 15, lhi = lane >> 4;
  size_t row0 = (size_t)blockIdx.x * 64;
  int coff = blockIdx.y * 512;
  const int KT  = (MODE == 1) ? 32 : 16;
  const int N16 = (MODE == 0) ? 64 : 32;
  const int CW  = (MODE == 0) ? 1024 : 512;
  f32x4 acc[4][8];
  #pragma unroll
  for (int mt = 0; mt < 4; ++mt)
    #pragma unroll
    for (int ct = 0; ct < 8; ++ct){
      f32x4 z = {0.f, 0.f, 0.f, 0.f};
      acc[mt][ct] = z;
    }
  for (int kt = 0; kt < KT; ++kt){
    const u16* As = A0; int kk = kt * 32;
    if (MODE == 1 && kt >= 16){ As = A1; kk = (kt - 16) * 32; }
    u16x8 af[4];
    #pragma unroll
    for (int mt = 0; mt < 4; ++mt)
      af[mt] = *(const u16x8*)&As[(row0 + mt * 16 + lrow) * 512 + kk + lhi * 8];
    #pragma unroll
    for (int ct = 0; ct < 8; ++ct){
      int ctg = (coff >> 4) + wave * 8 + ct;
      u16x8 bv = *(const u16x8*)&Bp[(((size_t)kt * N16 + ctg) * 64 + lane) * 8];
      #pragma unroll
      for (int mt = 0; mt < 4; ++mt) acc[mt][ct] = mfma16(af[mt], bv, acc[mt][ct]);
    }
  }
  #pragma unroll
  for (int ct = 0; ct < 8; ++ct){
    int c = coff + wave * 128 + ct * 16 + lrow;
    float bb = (MODE == 1) ? bias[c] : 0.f;
    #pragma unroll
    for (int mt = 0; mt < 4; ++mt)
      #pragma unroll
      for (int r = 0; r < 4; ++r){
        size_t grow = row0 + mt * 16 + lhi * 4 + r;
        float x = acc[mt][ct][r] + bb;
        if (MODE == 1) x = fmaxf(x, 0.f);
        Cout[grow * CW + c] = f2bf(x);
      }
  }
}

// Pack f32 weight [K][N] into MFMA B-fragment order (bf16):
// dst[((kt*(N/16)+ct)*64+lane)*8+j] = W[kt*32+(lane>>4)*8+j][ct*16+(lane&15)]
// w1mode: W'[k][c'] = c'<512 ? ew1[k][c'] : ew1[k+512][c'-512]  (P|Q weights)
__global__ void pack_w(const float* __restrict__ W, u16* __restrict__ dst,
                       int K, int N, int w1mode)
{
  int idx = blockIdx.x * 256 + threadIdx.x;
  int total = (K >> 5) * (N >> 4) * 64;
  if (idx >= total) return;
  int lane = idx & 63;
  int t = idx >> 6;
  int nt = N >> 4;
  int ct = t % nt;
  int kt = t / nt;
  int c  = ct * 16 + (lane & 15);
  int k0 = kt * 32 + (lane >> 4) * 8;
  u16x8 o;
  #pragma unroll
  for (int j = 0; j < 8; ++j){
    int k = k0 + j;
    float v;
    if (w1mode){
      v = (c < 512) ? W[(size_t)k * 512 + c] : W[(size_t)(k + 512) * 512 + (c - 512)];
    } else {
      v = W[(size_t)k * N + c];
    }
    o[j] = f2bf(v);
  }
  *(u16x8*)&dst[(size_t)idx * 8] = o;
}

__global__ void cast_node(const float* __restrict__ src, u16* __restrict__ dst, int n8){
  int idx = blockIdx.x * 256 + threadIdx.x;
  if (idx >= n8) return;
  const float4* s = (const float4*)src;
  float4 a = s[(size_t)idx * 2], b = s[(size_t)idx * 2 + 1];
  u16x8 o;
  o[0] = f2bf(a.x); o[1] = f2bf(a.y); o[2] = f2bf(a.z); o[3] = f2bf(a.w);
  o[4] = f2bf(b.x); o[5] = f2bf(b.y); o[6] = f2bf(b.z); o[7] = f2bf(b.w);
  *(u16x8*)&dst[(size_t)idx * 8] = o;
}

extern "C" void kernel_launch(void* const* d_in, const int* in_sizes, int n_in,
                              void* d_out, int out_size, void* d_ws, size_t ws_size,
                              hipStream_t stream)
{
  (void)in_sizes; (void)n_in; (void)out_size; (void)ws_size;
  const float* states = (const float*)d_in[0];
  const float* ew1 = (const float*)d_in[1];
  const float* eb1 = (const float*)d_in[2];
  const float* ew2 = (const float*)d_in[3];
  const float* eb2 = (const float*)d_in[4];
  const float* eg  = (const float*)d_in[5];
  const float* ebt = (const float*)d_in[6];
  const float* ew3 = (const float*)d_in[7];
  const float* eb3 = (const float*)d_in[8];
  const float* nw1 = (const float*)d_in[9];
  const float* nb1 = (const float*)d_in[10];
  const float* nw2 = (const float*)d_in[11];
  const float* nb2 = (const float*)d_in[12];
  const float* ng  = (const float*)d_in[13];
  const float* nbt = (const float*)d_in[14];
  const float* nw3 = (const float*)d_in[15];
  const float* nb3 = (const float*)d_in[16];
  const float* fnw = (const float*)d_in[17];
  const float* fnb = (const float*)d_in[18];
  const float* few = (const float*)d_in[19];
  const float* feb = (const float*)d_in[20];
  float* out = (float*)d_out;

  char* ws = (char*)d_ws;
  size_t off = 0;
  auto alloc = [&](size_t bytes) -> void* {
    void* p = ws + off;
    off += (bytes + 255) & ~(size_t)255;
    return p;
  };
  const size_t NV = 28672;  // B*n
  u16* PQ    = (u16*)alloc(NV * 1024 * 2);   // [NV][P(512)|Q(512)] bf16
  u16* nodeb = (u16*)alloc(NV * 512 * 2);
  u16* aggb  = (u16*)alloc(NV * 512 * 2);
  u16* r1h   = (u16*)alloc(NV * 512 * 2);
  u16* node2 = (u16*)alloc(NV * 512 * 2);
  u16* w1p   = (u16*)alloc(512 * 1024 * 2);
  u16* nw1p  = (u16*)alloc(1024 * 512 * 2);
  u16* w2p   = (u16*)alloc(512 * 512 * 2);
  u16* w3p   = (u16*)alloc(512 * 512 * 2);
  u16* nw2p  = (u16*)alloc(512 * 512 * 2);
  u16* nw3p  = (u16*)alloc(512 * 512 * 2);

  pack_w<<<256, 256, 0, stream>>>(ew1, w1p, 512, 1024, 1);
  pack_w<<<256, 256, 0, stream>>>(nw1, nw1p, 1024, 512, 0);
  pack_w<<<128, 256, 0, stream>>>(ew2, w2p, 512, 512, 0);
  pack_w<<<128, 256, 0, stream>>>(ew3, w3p, 512, 512, 0);
  pack_w<<<128, 256, 0, stream>>>(nw2, nw2p, 512, 512, 0);
  pack_w<<<128, 256, 0, stream>>>(nw3, nw3p, 512, 512, 0);
  cast_node<<<7168, 256, 0, stream>>>(states, nodeb, (int)(NV * 512 / 8));

  // Pass 1
  gemm64<0><<<dim3(448, 2), 256, 0, stream>>>(nodeb, nullptr, w1p, nullptr, PQ);
  edge_kernel<0><<<2048, 512, 0, stream>>>(PQ, w2p, w3p, eb1, eb2, eg, ebt, eb3,
                                           aggb, nullptr, nullptr, nullptr);
  // Node update
  gemm64<1><<<dim3(448, 1), 256, 0, stream>>>(nodeb, aggb, nw1p, nb1, r1h);
  node_tail<<<448, 512, 0, stream>>>(r1h, nw2p, nw3p, nb2, ng, nbt, nb3,
                                     fnw, fnb, node2, out);
  // Pass 2
  gemm64<0><<<dim3(448, 2), 256, 0, stream>>>(node2, nullptr, w1p, nullptr, PQ);
  edge_kernel<1><<<2048, 512, 0, stream>>>(PQ, w2p, w3p, eb1, eb2, eg, ebt, eb3,
                                           nullptr, few, feb, out);
}